// Round 3
// baseline (2868.198 us; speedup 1.0000x reference)
//
#include <hip/hip_runtime.h>
#include <cstdint>

// Problem constants
// B=32, C=32, O=32, N=512, L=128, K=2, DIL=2, PAD=2, EPS=1e-5
// x: (B,C,N,L) fp32. Outputs: residual (B,C,N,L) then skip (B,O,N,L), fp32.

typedef unsigned short ushort_t;
typedef unsigned int uint_t;

__device__ __forceinline__ float bf2f(uint_t u) {
  return __uint_as_float(u << 16);
}
__device__ __forceinline__ ushort_t f2bf(float f) {
  uint_t u = __float_as_uint(f);
  u += 0x7fffu + ((u >> 16) & 1u);   // RNE
  return (ushort_t)(u >> 16);
}

// ---------------------------------------------------------------------------
// K0: fold gc_w0/gc_w1/gc_b into skip/res weights.
//   A0s[o][c] = sum_k skip_w[o][k]*gc_w0[k][c]   (and A1s with gc_w1)
//   A0r/A1r likewise with res_w.
//   bs[o] = skip_w@gc_b + skip_b ; br[c] = res_w@gc_b + res_b
// Wc layout (floats): [0:1024)=A0s [1024:2048)=A1s [2048:3072)=A0r
//   [3072:4096)=A1r [4096:4128)=bs [4128:4160)=br [4160:4192)=bn_sum
//   [4192:4224)=bn_sq   (bn slots written by k2b)
// ---------------------------------------------------------------------------
__global__ __launch_bounds__(256) void k0(
    const float* __restrict__ gc_w0, const float* __restrict__ gc_w1,
    const float* __restrict__ gc_b, const float* __restrict__ skip_w,
    const float* __restrict__ skip_b, const float* __restrict__ res_w,
    const float* __restrict__ res_b, float* __restrict__ Wc) {
  const int t = threadIdx.x;
  for (int e = t; e < 4096; e += 256) {
    const int mat = e >> 10, idx = e & 1023, o = idx >> 5, ci = idx & 31;
    const float* left = (mat < 2) ? skip_w : res_w;
    const float* g = (mat & 1) ? gc_w1 : gc_w0;
    float s = 0.f;
    #pragma unroll
    for (int c = 0; c < 32; ++c) s = fmaf(left[o * 32 + c], g[c * 32 + ci], s);
    Wc[mat * 1024 + idx] = s;
  }
  if (t < 32) {
    float s = 0.f, r = 0.f;
    #pragma unroll
    for (int c = 0; c < 32; ++c) {
      s = fmaf(skip_w[t * 32 + c], gc_b[c], s);
      r = fmaf(res_w[t * 32 + c], gc_b[c], r);
    }
    Wc[4096 + t] = s + skip_b[t];
    Wc[4128 + t] = r + res_b[t];
  }
}

// ---------------------------------------------------------------------------
// K0b: convert supports S0,S1 (512x512 fp32, m contiguous) -> bf16 copies.
// Grid 256 x 256 threads x 4 elems.
// ---------------------------------------------------------------------------
__global__ __launch_bounds__(256) void k0b(const float* __restrict__ S0,
                                           const float* __restrict__ S1,
                                           ushort_t* __restrict__ S0b,
                                           ushort_t* __restrict__ S1b) {
  const int i = (blockIdx.x * 256 + threadIdx.x) * 4;
  const float4 a = *(const float4*)(S0 + i);
  const float4 c = *(const float4*)(S1 + i);
  ushort4 pa = make_ushort4(f2bf(a.x), f2bf(a.y), f2bf(a.z), f2bf(a.w));
  ushort4 pc = make_ushort4(f2bf(c.x), f2bf(c.y), f2bf(c.z), f2bf(c.w));
  *(ushort4*)(S0b + i) = pa;
  *(ushort4*)(S1b + i) = pc;
}

// ---------------------------------------------------------------------------
// K1a: transpose x (B,C,N,L) fp32 -> xT[b][l][c][n] bf16 (node index fastest).
// One block per (n-tile of 64, c, b). LDS tile [l][n] pitch 65 (conflict-free
// transposed reads).
// ---------------------------------------------------------------------------
__global__ __launch_bounds__(256) void k1a(const float* __restrict__ x,
                                           ushort_t* __restrict__ xT) {
  __shared__ float tile[128 * 65];
  const int nt = blockIdx.x, c = blockIdx.y, b = blockIdx.z;
  const int n0 = nt * 64, t = threadIdx.x;
  const int lq = t & 31, r = t >> 5;  // lanes -> l (coalesced global reads)
  const float* src = x + (((size_t)(b * 32 + c)) * 512 + n0) * 128;
  for (int nr = 0; nr < 8; ++nr) {
    const int nn = nr * 8 + r;
    const float4 v = *(const float4*)(src + nn * 128 + lq * 4);
    tile[(lq * 4 + 0) * 65 + nn] = v.x;
    tile[(lq * 4 + 1) * 65 + nn] = v.y;
    tile[(lq * 4 + 2) * 65 + nn] = v.z;
    tile[(lq * 4 + 3) * 65 + nn] = v.w;
  }
  __syncthreads();
  const int nn2 = t & 63, lg = t >> 6;
  ushort_t* dst = xT + (size_t)b * 128 * 16384 + (size_t)c * 512 + n0 + nn2;
  for (int i = 0; i < 32; ++i) {
    const int l = lg * 32 + i;
    dst[(size_t)l * 16384] = f2bf(tile[l * 65 + nn2]);
  }
}

// ---------------------------------------------------------------------------
// K1: gated causal dilated conv. h[b][l][o][n] (bf16, n fastest) =
//   tanh(conv_filt) * sigmoid(conv_gate), taps at l-2 and l.
// Block per (l, b); lanes -> n (coalesced). Weights are wave-uniform -> SGPR.
// ---------------------------------------------------------------------------
__global__ __launch_bounds__(256) void k1(
    const ushort_t* __restrict__ xT, const float* __restrict__ fw,
    const float* __restrict__ fb, const float* __restrict__ gw,
    const float* __restrict__ gb, ushort_t* __restrict__ hA) {
  const int l = blockIdx.x, b = blockIdx.y;
  const int t = threadIdx.x;
  const size_t plane = (size_t)(b * 128 + l) * 16384;
  const size_t planem2 = (size_t)(b * 128 + l - 2) * 16384;
  for (int half = 0; half < 2; ++half) {
    const int n = t + half * 256;
    float x0v[32], xmv[32];
    #pragma unroll
    for (int c = 0; c < 32; ++c) {
      x0v[c] = bf2f(xT[plane + c * 512 + n]);
      xmv[c] = (l >= 2) ? bf2f(xT[planem2 + c * 512 + n]) : 0.f;
    }
    #pragma unroll 4
    for (int o = 0; o < 32; ++o) {
      float f = fb[o], g = gb[o];
      #pragma unroll
      for (int c = 0; c < 32; ++c) {
        const float w0 = fw[(o * 32 + c) * 2], w1 = fw[(o * 32 + c) * 2 + 1];
        f = fmaf(w0, xmv[c], fmaf(w1, x0v[c], f));
        const float u0 = gw[(o * 32 + c) * 2], u1 = gw[(o * 32 + c) * 2 + 1];
        g = fmaf(u0, xmv[c], fmaf(u1, x0v[c], g));
      }
      const float e2f = __expf(2.f * f);
      const float th = 1.f - 2.f / (e2f + 1.f);     // tanh, overflow-safe
      const float sg = 1.f / (1.f + __expf(-g));    // sigmoid
      hA[plane + o * 512 + n] = f2bf(th * sg);
    }
  }
}

// ---------------------------------------------------------------------------
// K2: graph conv via MFMA. Per b: G0T/G1T[j][n] = sum_m hA[b][j][m]*S{0,1}[n][m]
// (j = l*32+c in [0,4096), m,n in [0,512)). Both operands bf16, k-contiguous:
//   A-frag: lane reads hA[j0+og*32+jg*16+(lane&15)][m0+(lane>>4)*8 ..+8]
//   B-frag: lane reads S[n0+ng*16+(lane&15)][m0+(lane>>4)*8 ..+8]
// No main-loop LDS/barriers: A re-reads are L2/L3-resident (hA=134MB<L3),
// S is 0.5MB (L2-hot). Wave og owns l-group l=jt*4+og (32 j-rows) x 64 n.
// Epilogue: dump frags (D: col=lane&15, row=(lane>>4)*4+reg) to g0_s/g1_s,
// then the verified fp32 channel-mix + BN partials + bf16 stores, unchanged.
// Grid flattened 8192 with bijective XCD swizzle (8192%8==0).
// ---------------------------------------------------------------------------
typedef __attribute__((ext_vector_type(8))) short bf16x8;
typedef __attribute__((ext_vector_type(4))) float f32x4;

__global__ __launch_bounds__(256) void k2(
    const ushort_t* __restrict__ hA, const ushort_t* __restrict__ S0b,
    const ushort_t* __restrict__ S1b, const float* __restrict__ Wc,
    ushort_t* __restrict__ skip_raw, ushort_t* __restrict__ res_raw,
    float* __restrict__ part) {
  __shared__ float sm[4352];
  float* g0_s = sm;          // [32][68] epilogue staging
  float* g1_s = sm + 2176;

  const int t = threadIdx.x;
  // XCD-aware swizzle: consecutive work-ids (sharing an A-panel across nt)
  // land on one XCD's L2. nwg=8192, 8192%8==0 -> bijective.
  const int w = (blockIdx.x & 7) * 1024 + (blockIdx.x >> 3);
  const int nt = w & 7, jt = (w >> 3) & 31, b = w >> 8;
  const int n0 = nt * 64, j0 = jt * 128;
  const int og = t >> 6, lane = t & 63;
  const int fr = lane & 15;        // fragment row (A) / col (B,D)
  const int kq = lane >> 4;        // k-quarter: k = kq*8 .. +8

  f32x4 acc0[2][4], acc1[2][4];
  #pragma unroll
  for (int jg = 0; jg < 2; ++jg)
    #pragma unroll
    for (int ng = 0; ng < 4; ++ng) {
      acc0[jg][ng] = {0.f, 0.f, 0.f, 0.f};
      acc1[jg][ng] = {0.f, 0.f, 0.f, 0.f};
    }

  const ushort_t* Ap = hA + (size_t)b * 4096 * 512 +
                       (size_t)(j0 + og * 32 + fr) * 512 + kq * 8;
  const ushort_t* B0p = S0b + (size_t)(n0 + fr) * 512 + kq * 8;
  const ushort_t* B1p = S1b + (size_t)(n0 + fr) * 512 + kq * 8;

  #pragma unroll 2
  for (int m0 = 0; m0 < 512; m0 += 32) {
    const bf16x8 a0 = *(const bf16x8*)(Ap + m0);
    const bf16x8 a1 = *(const bf16x8*)(Ap + 16 * 512 + m0);
    #pragma unroll
    for (int ng = 0; ng < 4; ++ng) {
      const bf16x8 b0 = *(const bf16x8*)(B0p + ng * 16 * 512 + m0);
      const bf16x8 b1 = *(const bf16x8*)(B1p + ng * 16 * 512 + m0);
      acc0[0][ng] =
          __builtin_amdgcn_mfma_f32_16x16x32_bf16(a0, b0, acc0[0][ng], 0, 0, 0);
      acc0[1][ng] =
          __builtin_amdgcn_mfma_f32_16x16x32_bf16(a1, b0, acc0[1][ng], 0, 0, 0);
      acc1[0][ng] =
          __builtin_amdgcn_mfma_f32_16x16x32_bf16(a0, b1, acc1[0][ng], 0, 0, 0);
      acc1[1][ng] =
          __builtin_amdgcn_mfma_f32_16x16x32_bf16(a1, b1, acc1[1][ng], 0, 0, 0);
    }
  }

  const float* A0s = Wc;
  const float* A1s = Wc + 1024;
  const float* A0r = Wc + 2048;
  const float* A1r = Wc + 3072;
  const float* bsv = Wc + 4096;
  const float* brv = Wc + 4128;
  const int n_i = lane;
  float accs[8], accq[8];
  #pragma unroll
  for (int oi = 0; oi < 8; ++oi) { accs[oi] = 0.f; accq[oi] = 0.f; }

  for (int lg = 0; lg < 4; ++lg) {  // l-group = one wave's 32 j-rows
    if (og == lg) {
      #pragma unroll
      for (int jg = 0; jg < 2; ++jg)
        #pragma unroll
        for (int ng = 0; ng < 4; ++ng)
          #pragma unroll
          for (int r = 0; r < 4; ++r) {
            const int c = jg * 16 + kq * 4 + r;   // D row -> channel
            const int nn = ng * 16 + fr;          // D col -> node
            g0_s[c * 68 + nn] = acc0[jg][ng][r];
            g1_s[c * 68 + nn] = acc1[jg][ng][r];
          }
    }
    __syncthreads();
    float sk[8], rs[8];
    #pragma unroll
    for (int oi = 0; oi < 8; ++oi) {
      sk[oi] = bsv[og * 8 + oi];
      rs[oi] = brv[og * 8 + oi];
    }
    for (int c = 0; c < 32; ++c) {
      const float v0 = g0_s[c * 68 + n_i];
      const float v1 = g1_s[c * 68 + n_i];
      #pragma unroll
      for (int oi = 0; oi < 8; ++oi) {
        const int o = og * 8 + oi;
        sk[oi] = fmaf(A0s[o * 32 + c], v0, fmaf(A1s[o * 32 + c], v1, sk[oi]));
        rs[oi] = fmaf(A0r[o * 32 + c], v0, fmaf(A1r[o * 32 + c], v1, rs[oi]));
      }
    }
    const int l = jt * 4 + lg;
    const size_t base = ((size_t)((b * 128 + l) * 32)) * 512 + n0 + n_i;
    #pragma unroll
    for (int oi = 0; oi < 8; ++oi) {
      const int o = og * 8 + oi;
      skip_raw[base + (size_t)o * 512] = f2bf(sk[oi]);
      res_raw[base + (size_t)o * 512] = f2bf(rs[oi]);
      accs[oi] += rs[oi];
      accq[oi] = fmaf(rs[oi], rs[oi], accq[oi]);
    }
    __syncthreads();
  }

  // per-wave lane reduction, one partial per (block, channel) — no atomics
  const int bidx = (b * 32 + jt) * 8 + nt;
  #pragma unroll
  for (int oi = 0; oi < 8; ++oi) {
    float s = accs[oi], q = accq[oi];
    for (int m = 1; m < 64; m <<= 1) {
      s += __shfl_xor(s, m, 64);
      q += __shfl_xor(q, m, 64);
    }
    if (n_i == 0) {
      part[(size_t)(og * 8 + oi) * 8192 + bidx] = s;
      part[(size_t)(32 + og * 8 + oi) * 8192 + bidx] = q;
    }
  }
}

// ---------------------------------------------------------------------------
// K2b: reduce BN partials -> Wc[4160+c] (sum), Wc[4192+c] (sumsq)
// ---------------------------------------------------------------------------
__global__ __launch_bounds__(256) void k2b(const float* __restrict__ part,
                                           float* __restrict__ Wc) {
  const int row = blockIdx.x;
  const int t = threadIdx.x;
  float s = 0.f;
  for (int i = t; i < 8192; i += 256) s += part[(size_t)row * 8192 + i];
  for (int m = 1; m < 64; m <<= 1) s += __shfl_xor(s, m, 64);
  __shared__ float red[4];
  if ((t & 63) == 0) red[t >> 6] = s;
  __syncthreads();
  if (t == 0) Wc[4160 + row] = red[0] + red[1] + red[2] + red[3];
}

// ---------------------------------------------------------------------------
// K3: transpose [b][l][ch][n] -> [b][ch][n][l]; BN + x-residual for res,
// passthrough for skip. Coalesced both sides via LDS (pitch 129).
// blockIdx.z = b*2 + tensor (0=res->residual, 1=skip).
// ---------------------------------------------------------------------------
__global__ __launch_bounds__(256) void k3(
    const ushort_t* __restrict__ skip_raw, const ushort_t* __restrict__ res_raw,
    const float* __restrict__ x, const float* __restrict__ Wc,
    const float* __restrict__ gamma, const float* __restrict__ beta,
    float* __restrict__ out) {
  __shared__ float tile[64 * 129];
  const int nt = blockIdx.x, ch = blockIdx.y, z = blockIdx.z;
  const int b = z >> 1, tensor = z & 1;
  const int n0 = nt * 64, t = threadIdx.x;
  const ushort_t* src = tensor ? skip_raw : res_raw;
  const int nn = t & 63, lg = t >> 6;
  const size_t sbase = (size_t)(b * 128) * 16384 + (size_t)ch * 512 + n0 + nn;
  for (int i = 0; i < 32; ++i) {
    const int l = lg * 32 + i;
    tile[nn * 129 + l] = bf2f(src[sbase + (size_t)l * 16384]);
  }
  __syncthreads();
  float scale = 1.f, shift = 0.f;
  if (tensor == 0) {
    const float s = Wc[4160 + ch], q = Wc[4192 + ch];
    const float mean = s * (1.f / 2097152.f);
    const float var = q * (1.f / 2097152.f) - mean * mean;
    scale = gamma[ch] * rsqrtf(var + 1e-5f);
    shift = beta[ch] - mean * scale;
  }
  const int l_ = t & 127, ng = t >> 7;
  float* dst = out + (tensor ? 67108864u : 0u);
  for (int j = 0; j < 32; ++j) {
    const int nq = ng * 32 + j;
    float v = tile[nq * 129 + l_] * scale + shift;
    const size_t idx = ((size_t)(b * 32 + ch) * 512 + n0 + nq) * 128 + l_;
    if (tensor == 0) v += x[idx];
    dst[idx] = v;
  }
}

// ---------------------------------------------------------------------------
extern "C" void kernel_launch(void* const* d_in, const int* in_sizes, int n_in,
                              void* d_out, int out_size, void* d_ws,
                              size_t ws_size, hipStream_t stream) {
  const float* x = (const float*)d_in[0];
  const float* S0 = (const float*)d_in[1];
  const float* S1 = (const float*)d_in[2];
  const float* fw = (const float*)d_in[3];
  const float* fb = (const float*)d_in[4];
  const float* gw = (const float*)d_in[5];
  const float* gb = (const float*)d_in[6];
  const float* gc_w0 = (const float*)d_in[7];
  const float* gc_w1 = (const float*)d_in[8];
  const float* gc_b = (const float*)d_in[9];
  const float* skip_w = (const float*)d_in[10];
  const float* skip_b = (const float*)d_in[11];
  const float* res_w = (const float*)d_in[12];
  const float* res_b = (const float*)d_in[13];
  const float* gamma = (const float*)d_in[14];
  const float* beta = (const float*)d_in[15];
  float* out = (float*)d_out;

  char* ws = (char*)d_ws;
  // ws layout: [0,32768) Wc | hA 134MB | xT/skip_raw 134MB | res_raw 134MB |
  //            part 2MB | S0b 512KB | S1b 512KB.  Total ~406MB.
  float* Wc = (float*)ws;
  ushort_t* hA = (ushort_t*)(ws + 32768);
  ushort_t* xT = (ushort_t*)(ws + 32768 + 134217728ull);  // reused as skip_raw
  ushort_t* res_raw = (ushort_t*)(ws + 32768 + 2ull * 134217728ull);
  float* part = (float*)(ws + 32768 + 3ull * 134217728ull);
  ushort_t* S0b = (ushort_t*)(ws + 32768 + 3ull * 134217728ull + 2097152ull);
  ushort_t* S1b = S0b + 262144;

  k0<<<1, 256, 0, stream>>>(gc_w0, gc_w1, gc_b, skip_w, skip_b, res_w, res_b,
                            Wc);
  k0b<<<256, 256, 0, stream>>>(S0, S1, S0b, S1b);
  k1a<<<dim3(8, 32, 32), 256, 0, stream>>>(x, xT);
  k1<<<dim3(128, 32), 256, 0, stream>>>(xT, fw, fb, gw, gb, hA);
  k2<<<8192, 256, 0, stream>>>(hA, S0b, S1b, Wc, xT /*skip_raw*/, res_raw,
                               part);
  k2b<<<64, 256, 0, stream>>>(part, Wc);
  k3<<<dim3(8, 32, 64), 256, 0, stream>>>(xT /*skip_raw*/, res_raw, x, Wc,
                                          gamma, beta, out);
}

// Round 4
// 2496.866 us; speedup vs baseline: 1.1487x; 1.1487x over previous
//
#include <hip/hip_runtime.h>
#include <cstdint>

// Problem constants
// B=32, C=32, O=32, N=512, L=128, K=2, DIL=2, PAD=2, EPS=1e-5
// x: (B,C,N,L) fp32. Outputs: residual (B,C,N,L) then skip (B,O,N,L), fp32.

typedef unsigned short ushort_t;
typedef unsigned int uint_t;

__device__ __forceinline__ float bf2f(uint_t u) {
  return __uint_as_float(u << 16);
}
__device__ __forceinline__ ushort_t f2bf(float f) {
  uint_t u = __float_as_uint(f);
  u += 0x7fffu + ((u >> 16) & 1u);   // RNE
  return (ushort_t)(u >> 16);
}

// ---------------------------------------------------------------------------
// K0: fold gc_w0/gc_w1/gc_b into skip/res weights.
// Wc layout (floats): [0:1024)=A0s [1024:2048)=A1s [2048:3072)=A0r
//   [3072:4096)=A1r [4096:4128)=bs [4128:4160)=br [4160:4192)=bn_sum
//   [4192:4224)=bn_sq   (bn slots written by k2b)
// ---------------------------------------------------------------------------
__global__ __launch_bounds__(256) void k0(
    const float* __restrict__ gc_w0, const float* __restrict__ gc_w1,
    const float* __restrict__ gc_b, const float* __restrict__ skip_w,
    const float* __restrict__ skip_b, const float* __restrict__ res_w,
    const float* __restrict__ res_b, float* __restrict__ Wc) {
  const int t = threadIdx.x;
  for (int e = t; e < 4096; e += 256) {
    const int mat = e >> 10, idx = e & 1023, o = idx >> 5, ci = idx & 31;
    const float* left = (mat < 2) ? skip_w : res_w;
    const float* g = (mat & 1) ? gc_w1 : gc_w0;
    float s = 0.f;
    #pragma unroll
    for (int c = 0; c < 32; ++c) s = fmaf(left[o * 32 + c], g[c * 32 + ci], s);
    Wc[mat * 1024 + idx] = s;
  }
  if (t < 32) {
    float s = 0.f, r = 0.f;
    #pragma unroll
    for (int c = 0; c < 32; ++c) {
      s = fmaf(skip_w[t * 32 + c], gc_b[c], s);
      r = fmaf(res_w[t * 32 + c], gc_b[c], r);
    }
    Wc[4096 + t] = s + skip_b[t];
    Wc[4128 + t] = r + res_b[t];
  }
}

// ---------------------------------------------------------------------------
// K0b: convert supports S0,S1 (512x512 fp32, m contiguous) -> bf16 copies.
// ---------------------------------------------------------------------------
__global__ __launch_bounds__(256) void k0b(const float* __restrict__ S0,
                                           const float* __restrict__ S1,
                                           ushort_t* __restrict__ S0b,
                                           ushort_t* __restrict__ S1b) {
  const int i = (blockIdx.x * 256 + threadIdx.x) * 4;
  const float4 a = *(const float4*)(S0 + i);
  const float4 c = *(const float4*)(S1 + i);
  ushort4 pa = make_ushort4(f2bf(a.x), f2bf(a.y), f2bf(a.z), f2bf(a.w));
  ushort4 pc = make_ushort4(f2bf(c.x), f2bf(c.y), f2bf(c.z), f2bf(c.w));
  *(ushort4*)(S0b + i) = pa;
  *(ushort4*)(S1b + i) = pc;
}

// ---------------------------------------------------------------------------
// K1a: transpose x (B,C,N,L) fp32 -> xT[b][l][c][n] bf16 (node index fastest).
// ---------------------------------------------------------------------------
__global__ __launch_bounds__(256) void k1a(const float* __restrict__ x,
                                           ushort_t* __restrict__ xT) {
  __shared__ float tile[128 * 65];
  const int nt = blockIdx.x, c = blockIdx.y, b = blockIdx.z;
  const int n0 = nt * 64, t = threadIdx.x;
  const int lq = t & 31, r = t >> 5;  // lanes -> l (coalesced global reads)
  const float* src = x + (((size_t)(b * 32 + c)) * 512 + n0) * 128;
  for (int nr = 0; nr < 8; ++nr) {
    const int nn = nr * 8 + r;
    const float4 v = *(const float4*)(src + nn * 128 + lq * 4);
    tile[(lq * 4 + 0) * 65 + nn] = v.x;
    tile[(lq * 4 + 1) * 65 + nn] = v.y;
    tile[(lq * 4 + 2) * 65 + nn] = v.z;
    tile[(lq * 4 + 3) * 65 + nn] = v.w;
  }
  __syncthreads();
  const int nn2 = t & 63, lg = t >> 6;
  ushort_t* dst = xT + (size_t)b * 128 * 16384 + (size_t)c * 512 + n0 + nn2;
  for (int i = 0; i < 32; ++i) {
    const int l = lg * 32 + i;
    dst[(size_t)l * 16384] = f2bf(tile[l * 65 + nn2]);
  }
}

// ---------------------------------------------------------------------------
// K1: gated causal dilated conv. h[b][l][o][n] (bf16, n fastest) =
//   tanh(conv_filt) * sigmoid(conv_gate), taps at l-2 and l.
// ---------------------------------------------------------------------------
__global__ __launch_bounds__(256) void k1(
    const ushort_t* __restrict__ xT, const float* __restrict__ fw,
    const float* __restrict__ fb, const float* __restrict__ gw,
    const float* __restrict__ gb, ushort_t* __restrict__ hA) {
  const int l = blockIdx.x, b = blockIdx.y;
  const int t = threadIdx.x;
  const size_t plane = (size_t)(b * 128 + l) * 16384;
  const size_t planem2 = (size_t)(b * 128 + l - 2) * 16384;
  for (int half = 0; half < 2; ++half) {
    const int n = t + half * 256;
    float x0v[32], xmv[32];
    #pragma unroll
    for (int c = 0; c < 32; ++c) {
      x0v[c] = bf2f(xT[plane + c * 512 + n]);
      xmv[c] = (l >= 2) ? bf2f(xT[planem2 + c * 512 + n]) : 0.f;
    }
    #pragma unroll 4
    for (int o = 0; o < 32; ++o) {
      float f = fb[o], g = gb[o];
      #pragma unroll
      for (int c = 0; c < 32; ++c) {
        const float w0 = fw[(o * 32 + c) * 2], w1 = fw[(o * 32 + c) * 2 + 1];
        f = fmaf(w0, xmv[c], fmaf(w1, x0v[c], f));
        const float u0 = gw[(o * 32 + c) * 2], u1 = gw[(o * 32 + c) * 2 + 1];
        g = fmaf(u0, xmv[c], fmaf(u1, x0v[c], g));
      }
      const float e2f = __expf(2.f * f);
      const float th = 1.f - 2.f / (e2f + 1.f);     // tanh, overflow-safe
      const float sg = 1.f / (1.f + __expf(-g));    // sigmoid
      hA[plane + o * 512 + n] = f2bf(th * sg);
    }
  }
}

// ---------------------------------------------------------------------------
// K2: graph conv via MFMA, LDS double-buffered 2-phase pipeline (T3 minimum).
// Per b: G0T/G1T[j][n] = sum_m hA[b][j][m]*S{0,1}[n][m].
// Tile 128(j) x 64(n) x {S0,S1}, BK=32, 16 K-steps.
// LDS staging (bf16, rows padded to 40 elems = 80B stride -> 2-way banks, free):
//   A  [2][128][40] @ smu + p*5120
//   B0 [2][64][40]  @ smu + 10240 + p*2560
//   B1 [2][64][40]  @ smu + 15360 + p*2560      total 40960 B
// Per K-step: issue next tile's 4 global loads -> ds_read frags + 16 MFMA ->
// ds_write next buffer -> one barrier. Loads' latency hides under MFMA phase.
// Epilogue (verified round-3): dump D frags (col=lane&15, row=(lane>>4)*4+reg)
// to g0_s/g1_s (aliases staging LDS), fp32 channel-mix + BN partials + stores.
// Grid flattened 8192 with bijective XCD swizzle (8192%8==0).
// ---------------------------------------------------------------------------
typedef __attribute__((ext_vector_type(8))) short bf16x8;
typedef __attribute__((ext_vector_type(4))) float f32x4;

__global__ __launch_bounds__(256) void k2(
    const ushort_t* __restrict__ hA, const ushort_t* __restrict__ S0b,
    const ushort_t* __restrict__ S1b, const float* __restrict__ Wc,
    ushort_t* __restrict__ skip_raw, ushort_t* __restrict__ res_raw,
    float* __restrict__ part) {
  __shared__ __align__(16) ushort_t smu[20480];   // 40960 B staging
  float* g0_s = (float*)smu;                      // epilogue alias [32][68]
  float* g1_s = (float*)smu + 2176;

  const int t = threadIdx.x;
  // XCD-aware swizzle: the 8 nt-blocks sharing an A-panel land on one XCD.
  const int w = (blockIdx.x & 7) * 1024 + (blockIdx.x >> 3);
  const int nt = w & 7, jt = (w >> 3) & 31, b = w >> 8;
  const int n0 = nt * 64, j0 = jt * 128;
  const int og = t >> 6, lane = t & 63;
  const int fr = lane & 15;        // fragment row (A) / col (B,D)
  const int kq = lane >> 4;        // k-quarter: k = kq*8 .. +8

  f32x4 acc0[2][4], acc1[2][4];
  #pragma unroll
  for (int jg = 0; jg < 2; ++jg)
    #pragma unroll
    for (int ng = 0; ng < 4; ++ng) {
      acc0[jg][ng] = {0.f, 0.f, 0.f, 0.f};
      acc1[jg][ng] = {0.f, 0.f, 0.f, 0.f};
    }

  // staging roles: thread t stages 16B chunks for row wrow, k-offset wkc
  const int wrow = t >> 2;          // 0..63
  const int wkc = (t & 3) * 8;      // 0/8/16/24 elements (16B chunks)
  const ushort_t* Ag0 = hA + (size_t)b * 4096 * 512 +
                        (size_t)(j0 + wrow) * 512 + wkc;
  const ushort_t* Ag1 = Ag0 + (size_t)64 * 512;
  const ushort_t* Bg0 = S0b + (size_t)(n0 + wrow) * 512 + wkc;
  const ushort_t* Bg1 = S1b + (size_t)(n0 + wrow) * 512 + wkc;
  const int wofs = wrow * 40 + wkc;

  // prologue: stage K-step 0 into buffer 0
  uint4 va0 = *(const uint4*)(Ag0);
  uint4 va1 = *(const uint4*)(Ag1);
  uint4 vb0 = *(const uint4*)(Bg0);
  uint4 vb1 = *(const uint4*)(Bg1);
  *(uint4*)(smu + wofs) = va0;
  *(uint4*)(smu + 64 * 40 + wofs) = va1;
  *(uint4*)(smu + 10240 + wofs) = vb0;
  *(uint4*)(smu + 15360 + wofs) = vb1;
  __syncthreads();

  int p = 0;
  for (int ks = 0; ks < 16; ++ks) {
    if (ks < 15) {  // issue next tile's global loads early (latency hides)
      const int m0 = (ks + 1) * 32;
      va0 = *(const uint4*)(Ag0 + m0);
      va1 = *(const uint4*)(Ag1 + m0);
      vb0 = *(const uint4*)(Bg0 + m0);
      vb1 = *(const uint4*)(Bg1 + m0);
    }
    const ushort_t* Ab = smu + p * 5120;
    const ushort_t* Bb0 = smu + 10240 + p * 2560;
    const ushort_t* Bb1 = smu + 15360 + p * 2560;
    const bf16x8 a0 = *(const bf16x8*)(Ab + (og * 32 + fr) * 40 + kq * 8);
    const bf16x8 a1 = *(const bf16x8*)(Ab + (og * 32 + 16 + fr) * 40 + kq * 8);
    #pragma unroll
    for (int ng = 0; ng < 4; ++ng) {
      const bf16x8 b0 = *(const bf16x8*)(Bb0 + (ng * 16 + fr) * 40 + kq * 8);
      const bf16x8 b1 = *(const bf16x8*)(Bb1 + (ng * 16 + fr) * 40 + kq * 8);
      acc0[0][ng] =
          __builtin_amdgcn_mfma_f32_16x16x32_bf16(a0, b0, acc0[0][ng], 0, 0, 0);
      acc0[1][ng] =
          __builtin_amdgcn_mfma_f32_16x16x32_bf16(a1, b0, acc0[1][ng], 0, 0, 0);
      acc1[0][ng] =
          __builtin_amdgcn_mfma_f32_16x16x32_bf16(a0, b1, acc1[0][ng], 0, 0, 0);
      acc1[1][ng] =
          __builtin_amdgcn_mfma_f32_16x16x32_bf16(a1, b1, acc1[1][ng], 0, 0, 0);
    }
    if (ks < 15) {  // write next tile to the other buffer, one barrier/K-step
      const int q = p ^ 1;
      *(uint4*)(smu + q * 5120 + wofs) = va0;
      *(uint4*)(smu + q * 5120 + 64 * 40 + wofs) = va1;
      *(uint4*)(smu + 10240 + q * 2560 + wofs) = vb0;
      *(uint4*)(smu + 15360 + q * 2560 + wofs) = vb1;
      __syncthreads();
      p = q;
    }
  }
  __syncthreads();  // staging LDS dead; epilogue aliases it

  const float* A0s = Wc;
  const float* A1s = Wc + 1024;
  const float* A0r = Wc + 2048;
  const float* A1r = Wc + 3072;
  const float* bsv = Wc + 4096;
  const float* brv = Wc + 4128;
  const int n_i = lane;
  float accs[8], accq[8];
  #pragma unroll
  for (int oi = 0; oi < 8; ++oi) { accs[oi] = 0.f; accq[oi] = 0.f; }

  for (int lg = 0; lg < 4; ++lg) {  // l-group = one wave's 32 j-rows
    if (og == lg) {
      #pragma unroll
      for (int jg = 0; jg < 2; ++jg)
        #pragma unroll
        for (int ng = 0; ng < 4; ++ng)
          #pragma unroll
          for (int r = 0; r < 4; ++r) {
            const int c = jg * 16 + kq * 4 + r;   // D row -> channel
            const int nn = ng * 16 + fr;          // D col -> node
            g0_s[c * 68 + nn] = acc0[jg][ng][r];
            g1_s[c * 68 + nn] = acc1[jg][ng][r];
          }
    }
    __syncthreads();
    float sk[8], rs[8];
    #pragma unroll
    for (int oi = 0; oi < 8; ++oi) {
      sk[oi] = bsv[og * 8 + oi];
      rs[oi] = brv[og * 8 + oi];
    }
    for (int c = 0; c < 32; ++c) {
      const float v0 = g0_s[c * 68 + n_i];
      const float v1 = g1_s[c * 68 + n_i];
      #pragma unroll
      for (int oi = 0; oi < 8; ++oi) {
        const int o = og * 8 + oi;
        sk[oi] = fmaf(A0s[o * 32 + c], v0, fmaf(A1s[o * 32 + c], v1, sk[oi]));
        rs[oi] = fmaf(A0r[o * 32 + c], v0, fmaf(A1r[o * 32 + c], v1, rs[oi]));
      }
    }
    const int l = jt * 4 + lg;
    const size_t base = ((size_t)((b * 128 + l) * 32)) * 512 + n0 + n_i;
    #pragma unroll
    for (int oi = 0; oi < 8; ++oi) {
      const int o = og * 8 + oi;
      skip_raw[base + (size_t)o * 512] = f2bf(sk[oi]);
      res_raw[base + (size_t)o * 512] = f2bf(rs[oi]);
      accs[oi] += rs[oi];
      accq[oi] = fmaf(rs[oi], rs[oi], accq[oi]);
    }
    __syncthreads();
  }

  // per-wave lane reduction, one partial per (block, channel) — no atomics
  const int bidx = (b * 32 + jt) * 8 + nt;
  #pragma unroll
  for (int oi = 0; oi < 8; ++oi) {
    float s = accs[oi], q = accq[oi];
    for (int m = 1; m < 64; m <<= 1) {
      s += __shfl_xor(s, m, 64);
      q += __shfl_xor(q, m, 64);
    }
    if (n_i == 0) {
      part[(size_t)(og * 8 + oi) * 8192 + bidx] = s;
      part[(size_t)(32 + og * 8 + oi) * 8192 + bidx] = q;
    }
  }
}

// ---------------------------------------------------------------------------
// K2b: reduce BN partials -> Wc[4160+c] (sum), Wc[4192+c] (sumsq)
// ---------------------------------------------------------------------------
__global__ __launch_bounds__(256) void k2b(const float* __restrict__ part,
                                           float* __restrict__ Wc) {
  const int row = blockIdx.x;
  const int t = threadIdx.x;
  float s = 0.f;
  for (int i = t; i < 8192; i += 256) s += part[(size_t)row * 8192 + i];
  for (int m = 1; m < 64; m <<= 1) s += __shfl_xor(s, m, 64);
  __shared__ float red[4];
  if ((t & 63) == 0) red[t >> 6] = s;
  __syncthreads();
  if (t == 0) Wc[4160 + row] = red[0] + red[1] + red[2] + red[3];
}

// ---------------------------------------------------------------------------
// K3: transpose [b][l][ch][n] -> [b][ch][n][l]; BN + x-residual for res,
// passthrough for skip. Coalesced both sides via LDS (pitch 129).
// ---------------------------------------------------------------------------
__global__ __launch_bounds__(256) void k3(
    const ushort_t* __restrict__ skip_raw, const ushort_t* __restrict__ res_raw,
    const float* __restrict__ x, const float* __restrict__ Wc,
    const float* __restrict__ gamma, const float* __restrict__ beta,
    float* __restrict__ out) {
  __shared__ float tile[64 * 129];
  const int nt = blockIdx.x, ch = blockIdx.y, z = blockIdx.z;
  const int b = z >> 1, tensor = z & 1;
  const int n0 = nt * 64, t = threadIdx.x;
  const ushort_t* src = tensor ? skip_raw : res_raw;
  const int nn = t & 63, lg = t >> 6;
  const size_t sbase = (size_t)(b * 128) * 16384 + (size_t)ch * 512 + n0 + nn;
  for (int i = 0; i < 32; ++i) {
    const int l = lg * 32 + i;
    tile[nn * 129 + l] = bf2f(src[sbase + (size_t)l * 16384]);
  }
  __syncthreads();
  float scale = 1.f, shift = 0.f;
  if (tensor == 0) {
    const float s = Wc[4160 + ch], q = Wc[4192 + ch];
    const float mean = s * (1.f / 2097152.f);
    const float var = q * (1.f / 2097152.f) - mean * mean;
    scale = gamma[ch] * rsqrtf(var + 1e-5f);
    shift = beta[ch] - mean * scale;
  }
  const int l_ = t & 127, ng = t >> 7;
  float* dst = out + (tensor ? 67108864u : 0u);
  for (int j = 0; j < 32; ++j) {
    const int nq = ng * 32 + j;
    float v = tile[nq * 129 + l_] * scale + shift;
    const size_t idx = ((size_t)(b * 32 + ch) * 512 + n0 + nq) * 128 + l_;
    if (tensor == 0) v += x[idx];
    dst[idx] = v;
  }
}

// ---------------------------------------------------------------------------
extern "C" void kernel_launch(void* const* d_in, const int* in_sizes, int n_in,
                              void* d_out, int out_size, void* d_ws,
                              size_t ws_size, hipStream_t stream) {
  const float* x = (const float*)d_in[0];
  const float* S0 = (const float*)d_in[1];
  const float* S1 = (const float*)d_in[2];
  const float* fw = (const float*)d_in[3];
  const float* fb = (const float*)d_in[4];
  const float* gw = (const float*)d_in[5];
  const float* gb = (const float*)d_in[6];
  const float* gc_w0 = (const float*)d_in[7];
  const float* gc_w1 = (const float*)d_in[8];
  const float* gc_b = (const float*)d_in[9];
  const float* skip_w = (const float*)d_in[10];
  const float* skip_b = (const float*)d_in[11];
  const float* res_w = (const float*)d_in[12];
  const float* res_b = (const float*)d_in[13];
  const float* gamma = (const float*)d_in[14];
  const float* beta = (const float*)d_in[15];
  float* out = (float*)d_out;

  char* ws = (char*)d_ws;
  // ws layout: [0,32768) Wc | hA 134MB | xT/skip_raw 134MB | res_raw 134MB |
  //            part 2MB | S0b 512KB | S1b 512KB.  Total ~406MB.
  float* Wc = (float*)ws;
  ushort_t* hA = (ushort_t*)(ws + 32768);
  ushort_t* xT = (ushort_t*)(ws + 32768 + 134217728ull);  // reused as skip_raw
  ushort_t* res_raw = (ushort_t*)(ws + 32768 + 2ull * 134217728ull);
  float* part = (float*)(ws + 32768 + 3ull * 134217728ull);
  ushort_t* S0b = (ushort_t*)(ws + 32768 + 3ull * 134217728ull + 2097152ull);
  ushort_t* S1b = S0b + 262144;

  k0<<<1, 256, 0, stream>>>(gc_w0, gc_w1, gc_b, skip_w, skip_b, res_w, res_b,
                            Wc);
  k0b<<<256, 256, 0, stream>>>(S0, S1, S0b, S1b);
  k1a<<<dim3(8, 32, 32), 256, 0, stream>>>(x, xT);
  k1<<<dim3(128, 32), 256, 0, stream>>>(xT, fw, fb, gw, gb, hA);
  k2<<<8192, 256, 0, stream>>>(hA, S0b, S1b, Wc, xT /*skip_raw*/, res_raw,
                               part);
  k2b<<<64, 256, 0, stream>>>(part, Wc);
  k3<<<dim3(8, 32, 64), 256, 0, stream>>>(xT /*skip_raw*/, res_raw, x, Wc,
                                          gamma, beta, out);
}